// Round 1
// baseline (2162.563 us; speedup 1.0000x reference)
//
#include <hip/hip_runtime.h>
#include <hip/hip_bf16.h>
#include <math.h>

// Problem constants: B=16, S=4096, E=512, NW=8, H=64 -> M = B*S = 65536, K = N = 512.
// Pipeline:
//   1. cvt x (fp32->bf16)                          [ws: xb]
//   2. gemm<0> x@W{q,k,v}^T + b, cos(.+theta[d])   -> q,k,v bf16 [ws]
//   3. attn per token (64 heads, d_k=8), writes rearranged layout -> attn_rs bf16 (reuses xb)
//   4. gemm<1> attn_rs@Wo^T + bo -> fp32 d_out
// ws usage: 64MiB(xb/attn_rs) + 3*64MiB(qkv) + 4*0.5MiB(weights) = ~258 MiB.

typedef __attribute__((ext_vector_type(8))) short short8;
typedef __attribute__((ext_vector_type(4))) float floatx4;
typedef __attribute__((ext_vector_type(4))) int intx4;

static __device__ __forceinline__ unsigned short f2bf(float f) {
  unsigned u = __float_as_uint(f);
  u += 0x7fffu + ((u >> 16) & 1u);   // RNE
  return (unsigned short)(u >> 16);
}
static __device__ __forceinline__ float bf2f(unsigned short h) {
  return __uint_as_float(((unsigned)h) << 16);
}

// ---------------- fp32 -> bf16 convert (vectorized, grid-stride) ----------------
__global__ void cvt_kernel(const float* __restrict__ in, unsigned short* __restrict__ out, int n) {
  int i0 = (blockIdx.x * blockDim.x + threadIdx.x) * 4;
  int stride = gridDim.x * blockDim.x * 4;
  for (int i = i0; i < n; i += stride) {
    const float4 v = *reinterpret_cast<const float4*>(in + i);
    ushort4 o;
    o.x = f2bf(v.x); o.y = f2bf(v.y); o.z = f2bf(v.z); o.w = f2bf(v.w);
    *reinterpret_cast<ushort4*>(out + i) = o;
  }
}

// ---------------- bf16 MFMA GEMM: C[m,n] = sum_k A[m,k]*W[n,k] (+epilogue) ----------------
// MODE 0: out_bf16 = cos(acc + bias[n] + theta[n&7])   (projection + quantum measure)
// MODE 1: out_f32  = acc + bias[n]                     (output projection)
// 128x128 tile, BK=64, 4 waves (2x2), 4x4 16x16x32 fragments per wave.
template<int MODE>
__global__ __launch_bounds__(256) void gemm_kernel(
    const unsigned short* __restrict__ A,   // [65536, 512] bf16 row-major
    const unsigned short* __restrict__ W,   // [512, 512] bf16 row-major (W[n][k])
    const float* __restrict__ bias,         // [512]
    const float* __restrict__ theta,        // [8] (MODE 0 only)
    unsigned short* __restrict__ outB,      // MODE 0
    float* __restrict__ outF)               // MODE 1
{
  // pad to 72 (144 B row stride = 9*16B): keeps 16B alignment, 2-way banks only (free)
  __shared__ unsigned short As[128][72];
  __shared__ unsigned short Bs[128][72];

  const int tid = threadIdx.x;
  const int bid = blockIdx.x;
  const int m0 = (bid >> 2) << 7;       // 512 m-blocks
  const int n0 = (bid & 3) << 7;        // 4 n-blocks

  const int lane = tid & 63;
  const int w = tid >> 6;
  const int wm = (w >> 1) << 6;
  const int wn = (w & 1) << 6;
  const int lr = lane & 15;             // frag row (A) / col (B/D)
  const int kg = lane >> 4;             // k-group 0..3

  floatx4 acc[4][4] = {};

  for (int k0 = 0; k0 < 512; k0 += 64) {
    // stage 128x64 bf16 of A and W: 256 thr * 4 chunks * 16B each
    #pragma unroll
    for (int it = 0; it < 4; ++it) {
      int chunk = tid + it * 256;       // 0..1023
      int row = chunk >> 3;             // 0..127
      int col = (chunk & 7) << 3;       // 0..56
      *reinterpret_cast<intx4*>(&As[row][col]) =
          *reinterpret_cast<const intx4*>(&A[(size_t)(m0 + row) * 512 + k0 + col]);
      *reinterpret_cast<intx4*>(&Bs[row][col]) =
          *reinterpret_cast<const intx4*>(&W[(size_t)(n0 + row) * 512 + k0 + col]);
    }
    __syncthreads();

    #pragma unroll
    for (int kk = 0; kk < 64; kk += 32) {
      short8 af[4], bfr[4];
      #pragma unroll
      for (int mi = 0; mi < 4; ++mi)
        af[mi] = *reinterpret_cast<const short8*>(&As[wm + mi * 16 + lr][kk + kg * 8]);
      #pragma unroll
      for (int ni = 0; ni < 4; ++ni)
        bfr[ni] = *reinterpret_cast<const short8*>(&Bs[wn + ni * 16 + lr][kk + kg * 8]);
      #pragma unroll
      for (int mi = 0; mi < 4; ++mi)
        #pragma unroll
        for (int ni = 0; ni < 4; ++ni)
          acc[mi][ni] = __builtin_amdgcn_mfma_f32_16x16x32_bf16(af[mi], bfr[ni], acc[mi][ni], 0, 0, 0);
    }
    __syncthreads();
  }

  // epilogue: D layout row=(lane>>4)*4+i, col=lane&15 (m89-verified)
  float bl[4];
  #pragma unroll
  for (int ni = 0; ni < 4; ++ni) bl[ni] = bias[n0 + wn + ni * 16 + lr];
  float thl = 0.0f;
  if constexpr (MODE == 0) thl = theta[lr & 7];   // (n & 7) == (lr & 7) since n-lr is mult of 16

  #pragma unroll
  for (int mi = 0; mi < 4; ++mi) {
    #pragma unroll
    for (int ni = 0; ni < 4; ++ni) {
      #pragma unroll
      for (int i = 0; i < 4; ++i) {
        int gm = m0 + wm + mi * 16 + kg * 4 + i;
        int gn = n0 + wn + ni * 16 + lr;
        float val = acc[mi][ni][i] + bl[ni];
        if constexpr (MODE == 0) {
          outB[(size_t)gm * 512 + gn] = f2bf(cosf(val + thl));
        } else {
          outF[(size_t)gm * 512 + gn] = val;
        }
      }
    }
  }
}

// ---------------- per-token cross-head attention ----------------
// One wave per token; lane = head. scores[64] in registers (fully unrolled).
// Writes output already rearranged: out[b][h*64 + s/64][(s%64)*8 + d].
__global__ __launch_bounds__(256) void attn_kernel(
    const unsigned short* __restrict__ q,
    const unsigned short* __restrict__ k,
    const unsigned short* __restrict__ v,
    unsigned short* __restrict__ out)
{
  __shared__ float kf[4][64][9];   // +1 pad
  __shared__ float vf[4][64][9];
  const int w = threadIdx.x >> 6;
  const int lane = threadIdx.x & 63;
  const int t = blockIdx.x * 4 + w;            // token id, 0..65535

  const size_t base = (size_t)t * 512 + lane * 8;
  short8 q8 = *reinterpret_cast<const short8*>(q + base);
  short8 k8 = *reinterpret_cast<const short8*>(k + base);
  short8 v8 = *reinterpret_cast<const short8*>(v + base);

  float qf[8];
  #pragma unroll
  for (int d = 0; d < 8; ++d) {
    qf[d] = bf2f((unsigned short)q8[d]);
    kf[w][lane][d] = bf2f((unsigned short)k8[d]);
    vf[w][lane][d] = bf2f((unsigned short)v8[d]);
  }
  __syncthreads();

  float s[64];
  #pragma unroll
  for (int j = 0; j < 64; ++j) {
    float a = 0.f;
    #pragma unroll
    for (int d = 0; d < 8; ++d) a += qf[d] * kf[w][j][d];   // LDS broadcast reads
    s[j] = a;
  }
  float m = s[0];
  #pragma unroll
  for (int j = 1; j < 64; ++j) m = fmaxf(m, s[j]);

  const float c = 0.35355339059327f * 1.44269504089f;  // (1/sqrt(8)) * log2(e)
  float o[8] = {0, 0, 0, 0, 0, 0, 0, 0};
  float sum = 0.f;
  #pragma unroll
  for (int j = 0; j < 64; ++j) {
    float p = exp2f((s[j] - m) * c);
    sum += p;
    #pragma unroll
    for (int d = 0; d < 8; ++d) o[d] += p * vf[w][j][d];
  }
  const float inv = 1.0f / sum;

  const int b = t >> 12;
  const int sidx = t & 4095;
  const int sb = sidx >> 6, si = sidx & 63;
  const size_t row = (size_t)(b << 12) + (lane << 6) + sb;   // h = lane
  short8 o8;
  #pragma unroll
  for (int d = 0; d < 8; ++d) o8[d] = (short)f2bf(o[d] * inv);
  *reinterpret_cast<short8*>(out + row * 512 + si * 8) = o8;
}

extern "C" void kernel_launch(void* const* d_in, const int* in_sizes, int n_in,
                              void* d_out, int out_size, void* d_ws, size_t ws_size,
                              hipStream_t stream) {
  const float* x     = (const float*)d_in[0];
  const float* Wq    = (const float*)d_in[1];
  const float* bq    = (const float*)d_in[2];
  const float* Wk    = (const float*)d_in[3];
  const float* bk    = (const float*)d_in[4];
  const float* Wv    = (const float*)d_in[5];
  const float* bv    = (const float*)d_in[6];
  const float* Wo    = (const float*)d_in[7];
  const float* bo    = (const float*)d_in[8];
  const float* theta = (const float*)d_in[9];
  float* out = (float*)d_out;

  char* ws = (char*)d_ws;
  const size_t MB = 1024ull * 1024ull;
  unsigned short* xb  = (unsigned short*)(ws);             // 64 MiB; reused as attn_rs
  unsigned short* qb  = (unsigned short*)(ws + 64 * MB);
  unsigned short* kb  = (unsigned short*)(ws + 128 * MB);
  unsigned short* vb  = (unsigned short*)(ws + 192 * MB);
  unsigned short* wqb = (unsigned short*)(ws + 256 * MB);
  unsigned short* wkb = (unsigned short*)(ws + 256 * MB + 512 * 1024);
  unsigned short* wvb = (unsigned short*)(ws + 257 * MB);
  unsigned short* wob = (unsigned short*)(ws + 257 * MB + 512 * 1024);

  const int NX = 65536 * 512;
  const int NW2 = 512 * 512;

  cvt_kernel<<<2048, 256, 0, stream>>>(x, xb, NX);
  cvt_kernel<<<256, 256, 0, stream>>>(Wq, wqb, NW2);
  cvt_kernel<<<256, 256, 0, stream>>>(Wk, wkb, NW2);
  cvt_kernel<<<256, 256, 0, stream>>>(Wv, wvb, NW2);
  cvt_kernel<<<256, 256, 0, stream>>>(Wo, wob, NW2);

  gemm_kernel<0><<<2048, 256, 0, stream>>>(xb, wqb, bq, theta, qb, nullptr);
  gemm_kernel<0><<<2048, 256, 0, stream>>>(xb, wkb, bk, theta, kb, nullptr);
  gemm_kernel<0><<<2048, 256, 0, stream>>>(xb, wvb, bv, theta, vb, nullptr);

  attn_kernel<<<16384, 256, 0, stream>>>(qb, kb, vb, xb);   // writes rearranged A for gemm2

  gemm_kernel<1><<<2048, 256, 0, stream>>>(xb, wob, bo, nullptr, nullptr, out);
}

// Round 3
// 2018.877 us; speedup vs baseline: 1.0712x; 1.0712x over previous
//
#include <hip/hip_runtime.h>
#include <hip/hip_bf16.h>
#include <math.h>

// B=16, S=4096, E=512, NW=8, H=64 -> M = B*S = 65536, K = 512.
// Pipeline:
//   1. cvt x, Wq, Wk, Wv, Wo (fp32->bf16)                      [ws]
//   2. gemm<0> fused QKV: x@W{q,k,v}^T + b, cos(.+theta)       -> q,k,v bf16 [ws]
//   3. attn per token (64 heads, d_k=8) -> rearranged bf16 (reuses xb)
//   4. gemm<1> attn_rs@Wo^T + bo -> fp32 d_out
//
// R1 post-mortem: reg-staged LDS fills spilled (VGPR_Count=64, 1.87 GB scratch
// writes per GEMM, MfmaUtil 2.6%). R2: m97 structure -- global_load_lds direct
// staging, linear LDS, launch_bounds(256,1). (R2 failed on a 7-vs-8 arg launch
// typo; R3 is R2 with the call fixed.)

typedef __attribute__((ext_vector_type(8))) short short8;
typedef __attribute__((ext_vector_type(4))) float floatx4;

static __device__ __forceinline__ unsigned short f2bf(float f) {
  unsigned u = __float_as_uint(f);
  u += 0x7fffu + ((u >> 16) & 1u);   // RNE
  return (unsigned short)(u >> 16);
}
static __device__ __forceinline__ float bf2f(unsigned short h) {
  return __uint_as_float(((unsigned)h) << 16);
}

static __device__ __forceinline__ void gload16(const void* g, void* l) {
  __builtin_amdgcn_global_load_lds(
      (const __attribute__((address_space(1))) void*)g,
      (__attribute__((address_space(3))) void*)l, 16, 0, 0);
}

// ---------------- fp32 -> bf16 convert ----------------
__global__ void cvt_kernel(const float* __restrict__ in, unsigned short* __restrict__ out, int n) {
  int i0 = (blockIdx.x * blockDim.x + threadIdx.x) * 4;
  int stride = gridDim.x * blockDim.x * 4;
  for (int i = i0; i < n; i += stride) {
    const float4 v = *reinterpret_cast<const float4*>(in + i);
    ushort4 o;
    o.x = f2bf(v.x); o.y = f2bf(v.y); o.z = f2bf(v.z); o.w = f2bf(v.w);
    *reinterpret_cast<ushort4*>(out + i) = o;
  }
}

// ---------------- bf16 MFMA GEMM (m97 structure) ----------------
// MODE 0: fused QKV. W0 = wqb, with wkb/wvb contiguous at +256K elems.
//         o0 = qb, with kb/vb contiguous at +32M elems. NBLK=12.
//         out = cos(acc + bias[n] + theta[n&7]) as bf16.
// MODE 1: out projection. outF = acc + bias[n], fp32. NBLK=4.
// 128x128 tile, BK=64, 4 waves (2x2), 4x4 16x16x32 frags.
template<int MODE, int NBLK>
__global__ __launch_bounds__(256, 1) void gemm_kernel(
    const unsigned short* __restrict__ A,    // [65536, 512] bf16
    const unsigned short* __restrict__ W0,   // [512,512] x (MODE0?3:1), row-major [n][k]
    const float* __restrict__ b0,
    const float* __restrict__ b1,
    const float* __restrict__ b2,
    const float* __restrict__ theta,
    unsigned short* __restrict__ o0,         // MODE 0
    float* __restrict__ outF)                // MODE 1
{
  __shared__ unsigned short As[128 * 64];    // linear: row-major [128][64], 16 KiB
  __shared__ unsigned short Bs[128 * 64];

  const int tid = threadIdx.x;
  const int bid = blockIdx.x;
  const int m_blk = bid / NBLK;
  const int n_blk = bid - m_blk * NBLK;
  const int m0 = m_blk << 7;

  const unsigned short* W;
  const float* bias;
  int n0, wsel = 0;
  if constexpr (MODE == 0) {
    wsel = n_blk >> 2;                 // 0=Q 1=K 2=V
    n0 = (n_blk & 3) << 7;
    W = W0 + (size_t)wsel * 262144;
    bias = (wsel == 0) ? b0 : ((wsel == 1) ? b1 : b2);
  } else {
    W = W0; bias = b0; n0 = n_blk << 7;
  }

  const int lane = tid & 63;
  const int w = tid >> 6;
  const int wm = (w >> 1) << 6;
  const int wn = (w & 1) << 6;
  const int lr = lane & 15;
  const int kg = lane >> 4;

  // staging geometry: chunk = i*4+w covers 8 rows (512 elems = 1024 B);
  // lane covers row rowb+(lane>>3), col (lane&7)*8 -> linear LDS order.
  const int srow = lane >> 3;
  const int scol = (lane & 7) << 3;

  floatx4 acc[4][4] = {};

  for (int k0 = 0; k0 < 512; k0 += 64) {
    #pragma unroll
    for (int i = 0; i < 4; ++i) {
      const int chunk = (i << 2) | w;          // 0..15
      const int row = (chunk << 3) + srow;
      gload16(&A[(size_t)(m0 + row) * 512 + k0 + scol], &As[chunk << 9]);
      gload16(&W[(size_t)(n0 + row) * 512 + k0 + scol], &Bs[chunk << 9]);
    }
    __syncthreads();

    #pragma unroll
    for (int kk = 0; kk < 64; kk += 32) {
      short8 af[4], bfr[4];
      #pragma unroll
      for (int mi = 0; mi < 4; ++mi)
        af[mi] = *reinterpret_cast<const short8*>(&As[(wm + mi * 16 + lr) * 64 + kk + kg * 8]);
      #pragma unroll
      for (int ni = 0; ni < 4; ++ni)
        bfr[ni] = *reinterpret_cast<const short8*>(&Bs[(wn + ni * 16 + lr) * 64 + kk + kg * 8]);
      #pragma unroll
      for (int mi = 0; mi < 4; ++mi)
        #pragma unroll
        for (int ni = 0; ni < 4; ++ni)
          acc[mi][ni] = __builtin_amdgcn_mfma_f32_16x16x32_bf16(af[mi], bfr[ni], acc[mi][ni], 0, 0, 0);
    }
    __syncthreads();
  }

  float bl[4];
  #pragma unroll
  for (int ni = 0; ni < 4; ++ni) bl[ni] = bias[n0 + wn + ni * 16 + lr];
  float thl = 0.0f;
  if constexpr (MODE == 0) thl = theta[lr & 7];   // gn === lr (mod 8)

  #pragma unroll
  for (int mi = 0; mi < 4; ++mi) {
    #pragma unroll
    for (int ni = 0; ni < 4; ++ni) {
      #pragma unroll
      for (int i = 0; i < 4; ++i) {
        int gm = m0 + wm + mi * 16 + kg * 4 + i;
        int gn = n0 + wn + ni * 16 + lr;
        float val = acc[mi][ni][i] + bl[ni];
        if constexpr (MODE == 0) {
          o0[(size_t)wsel * 33554432 + (size_t)gm * 512 + gn] = f2bf(cosf(val + thl));
        } else {
          outF[(size_t)gm * 512 + gn] = val;
        }
      }
    }
  }
}

// ---------------- per-token cross-head attention ----------------
__global__ __launch_bounds__(256) void attn_kernel(
    const unsigned short* __restrict__ q,
    const unsigned short* __restrict__ k,
    const unsigned short* __restrict__ v,
    unsigned short* __restrict__ out)
{
  __shared__ float kf[4][64][9];
  __shared__ float vf[4][64][9];
  const int w = threadIdx.x >> 6;
  const int lane = threadIdx.x & 63;
  const int t = blockIdx.x * 4 + w;

  const size_t base = (size_t)t * 512 + lane * 8;
  short8 q8 = *reinterpret_cast<const short8*>(q + base);
  short8 k8 = *reinterpret_cast<const short8*>(k + base);
  short8 v8 = *reinterpret_cast<const short8*>(v + base);

  float qf[8];
  #pragma unroll
  for (int d = 0; d < 8; ++d) {
    qf[d] = bf2f((unsigned short)q8[d]);
    kf[w][lane][d] = bf2f((unsigned short)k8[d]);
    vf[w][lane][d] = bf2f((unsigned short)v8[d]);
  }
  __syncthreads();

  float s[64];
  #pragma unroll
  for (int j = 0; j < 64; ++j) {
    float a = 0.f;
    #pragma unroll
    for (int d = 0; d < 8; ++d) a += qf[d] * kf[w][j][d];
    s[j] = a;
  }
  float m = s[0];
  #pragma unroll
  for (int j = 1; j < 64; ++j) m = fmaxf(m, s[j]);

  const float c = 0.35355339059327f * 1.44269504089f;  // (1/sqrt(8)) * log2(e)
  float o[8] = {0, 0, 0, 0, 0, 0, 0, 0};
  float sum = 0.f;
  #pragma unroll
  for (int j = 0; j < 64; ++j) {
    float p = exp2f((s[j] - m) * c);
    sum += p;
    #pragma unroll
    for (int d = 0; d < 8; ++d) o[d] += p * vf[w][j][d];
  }
  const float inv = 1.0f / sum;

  const int b = t >> 12;
  const int sidx = t & 4095;
  const int sb = sidx >> 6, si = sidx & 63;
  const size_t row = (size_t)(b << 12) + (lane << 6) + sb;   // h = lane
  short8 o8;
  #pragma unroll
  for (int d = 0; d < 8; ++d) o8[d] = (short)f2bf(o[d] * inv);
  *reinterpret_cast<short8*>(out + row * 512 + si * 8) = o8;
}

extern "C" void kernel_launch(void* const* d_in, const int* in_sizes, int n_in,
                              void* d_out, int out_size, void* d_ws, size_t ws_size,
                              hipStream_t stream) {
  const float* x     = (const float*)d_in[0];
  const float* Wq    = (const float*)d_in[1];
  const float* bq    = (const float*)d_in[2];
  const float* Wk    = (const float*)d_in[3];
  const float* bk    = (const float*)d_in[4];
  const float* Wv    = (const float*)d_in[5];
  const float* bv    = (const float*)d_in[6];
  const float* Wo    = (const float*)d_in[7];
  const float* bo    = (const float*)d_in[8];
  const float* theta = (const float*)d_in[9];
  float* out = (float*)d_out;

  char* ws = (char*)d_ws;
  const size_t MB = 1024ull * 1024ull;
  unsigned short* xb  = (unsigned short*)(ws);             // 64 MiB; reused as attn_rs
  unsigned short* qb  = (unsigned short*)(ws + 64 * MB);   // q,k,v contiguous (64 MiB each)
  unsigned short* wqb = (unsigned short*)(ws + 256 * MB);  // wq,wk,wv contiguous (512 KiB each)
  unsigned short* wkb = wqb + 262144;
  unsigned short* wvb = wqb + 524288;
  unsigned short* wob = wqb + 786432;

  const int NX = 65536 * 512;
  const int NW2 = 512 * 512;

  cvt_kernel<<<2048, 256, 0, stream>>>(x, xb, NX);
  cvt_kernel<<<256, 256, 0, stream>>>(Wq, wqb, NW2);
  cvt_kernel<<<256, 256, 0, stream>>>(Wk, wkb, NW2);
  cvt_kernel<<<256, 256, 0, stream>>>(Wv, wvb, NW2);
  cvt_kernel<<<256, 256, 0, stream>>>(Wo, wob, NW2);

  // fused QKV projection: N = 1536, grid = 512 m-blocks x 12 n-blocks
  gemm_kernel<0, 12><<<6144, 256, 0, stream>>>(xb, wqb, bq, bk, bv, theta, qb, nullptr);

  attn_kernel<<<16384, 256, 0, stream>>>(qb, qb + 33554432, qb + 67108864, xb);

  // output projection: N = 512, grid = 512 x 4
  gemm_kernel<1, 4><<<2048, 256, 0, stream>>>(xb, wob, bo, nullptr, nullptr, nullptr, nullptr, out);
}